// Round 13
// baseline (106.985 us; speedup 1.0000x reference)
//
#include <hip/hip_runtime.h>
#include <hip/hip_bf16.h>

#define TD_B 512

typedef __bf16 bf16x8 __attribute__((ext_vector_type(8)));
typedef __bf16 bf16x4 __attribute__((ext_vector_type(4)));
typedef float  f32x4  __attribute__((ext_vector_type(4)));

#define MFMA(a, b, c) __builtin_amdgcn_mfma_f32_16x16x32_bf16((a), (b), (c), 0, 0, 0)

__device__ __forceinline__ float sigf(float x)  { return 1.0f / (1.0f + __expf(-x)); }
__device__ __forceinline__ float tanhf_(float x){ return 2.0f / (1.0f + __expf(-2.0f * x)) - 1.0f; }

extern "C" __global__ void __launch_bounds__(128, 2)
traj_disc_kernel(const float* __restrict__ x, const float* __restrict__ dmat,
                 const float* __restrict__ bmat, const float* __restrict__ hmat,
                 const float* __restrict__ mask,
                 const float* __restrict__ emb_w, const float* __restrict__ emb_b,
                 const float* __restrict__ w_ih, const float* __restrict__ w_hh,
                 const float* __restrict__ b_ih, const float* __restrict__ b_hh,
                 const float* __restrict__ e2a_w, const float* __restrict__ e2a_b,
                 const float* __restrict__ dom,
                 const float* __restrict__ sp_w, const float* __restrict__ sp_b,
                 const float* __restrict__ a2e_w, const float* __restrict__ a2e_b,
                 const float* __restrict__ w1, const float* __restrict__ b1,
                 const float* __restrict__ w2, const float* __restrict__ b2,
                 const float* __restrict__ w3, const float* __restrict__ b3,
                 float* __restrict__ out)
{
    const int b    = blockIdx.x;
    const int tid  = threadIdx.x;    // 0..127
    const int lane = tid & 63;
    const int w    = tid >> 6;       // wave 0..1
    const int l15  = lane & 15;
    const int lg   = lane >> 4;      // 0..3

    __shared__ __bf16 sAin[32][72];   // 0-15 xe | 16-47 h | 48 ones | 49-63 zero
    __shared__ __bf16 sHl [32][40];
    __shared__ __bf16 sWN [32][40];
    __shared__ __bf16 sHaT[32][40];
    __shared__ __bf16 sEmb[32][40];
    __shared__ __bf16 sPA [32][72];   // 0-31 ha | 32-63 att
    __shared__ float  sMaskT[20][36];
    __shared__ float  sDom[144];
    __shared__ __bf16 z1bf[32][136];
    __shared__ __bf16 z2bf[32][136];
    __shared__ int    sFlag;

    // ---- staging ----
    if (tid == 0) sFlag = 1;
    for (int idx = tid; idx < 32 * 72; idx += 128)
        (&sAin[0][0])[idx] = (idx % 72 == 48) ? (__bf16)1.0f : (__bf16)0.0f;
    for (int idx = tid; idx < 640; idx += 128) {
        int tt = idx >> 5, n = idx & 31;
        sMaskT[tt][n] = mask[(b * 32 + n) * 20 + tt];
    }
    if (tid < 128) for (int idx = tid; idx < 144; idx += 128) sDom[idx] = dom[idx];
    __syncthreads();
    // uniformity check: dom all-equal AND mask all-ones (block-uniform result)
    {
        const float d0 = sDom[0];
        bool ok = true;
        for (int i = tid; i < 144; i += 128) ok &= (sDom[i] == d0);
        for (int i = tid; i < 640; i += 128) ok &= ((&sMaskT[0][0])[(i >> 5) * 36 + (i & 31)] == 1.0f);
        if (!ok) sFlag = 0;
    }

    // phase-A per-thread mapping: row i0, 8-col group q0, 4-col xe group e0
    const int i0 = tid >> 2, q0 = (tid & 3) * 8, e0 = (tid & 3) * 4;
    const float dom0 = dom[0];
    float ewa[4], ewb[4], ebb[4];
    #pragma unroll
    for (int k = 0; k < 4; ++k) {
        ewa[k] = emb_w[e0 + k];
        ewb[k] = emb_w[16 + e0 + k];
        ebb[k] = emb_b[e0 + k];
    }

    // ---- transposed-gates A-fragments: wave owns 4 col-tiles (c=(4w+mtl)*16+l15, c=4h+g) ----
    bf16x8 Ag[4][2];
    #pragma unroll
    for (int mtl = 0; mtl < 4; ++mtl) {
        int c  = (4 * w + mtl) * 16 + l15;
        int cg = (c & 3) * 32 + (c >> 2);
        #pragma unroll
        for (int kt = 0; kt < 2; ++kt)
            #pragma unroll
            for (int j = 0; j < 8; ++j) {
                int k = kt * 32 + lg * 8 + j;
                float v;
                if (k < 16)       v = w_ih[k * 128 + cg];
                else if (k < 48)  v = w_hh[(k - 16) * 128 + cg];
                else if (k == 48) v = b_ih[cg] + b_hh[cg];
                else              v = 0.0f;
                Ag[mtl][kt][j] = (__bf16)v;
            }
    }
    // C/D/E/F: wave owns col-half cw, loops both row-halves mtw
    const int cw = w * 16 + l15;
    bf16x8 Be2a, Ba2e, Bsp[2];
    #pragma unroll
    for (int j = 0; j < 8; ++j) {
        Be2a[j] = (__bf16)e2a_w[(lg * 8 + j) * 32 + cw];
        Ba2e[j] = (__bf16)a2e_w[(lg * 8 + j) * 32 + cw];
    }
    #pragma unroll
    for (int kt = 0; kt < 2; ++kt)
        #pragma unroll
        for (int j = 0; j < 8; ++j)
            Bsp[kt][j] = (__bf16)sp_w[(kt * 32 + lg * 8 + j) * 32 + cw];
    const float bEw = e2a_b[cw], bSw = sp_b[cw], bAw = a2e_b[cw];

    float cst[4][2] = {};             // cell state [mtl][nt], lane-local
    f32x4 accZ[2][4] = {};            // online z1 [mt][ct]
    bf16x8 Bw1cur[4];

    // incremental pointers
    const float* dp = dmat + ((long)(b * 32 + i0) * 20) * 32 + q0;
    const float* bp = bmat + ((long)(b * 32 + i0) * 20) * 32 + q0;
    const float* hp = hmat + ((long)(b * 32 + i0) * 20) * 32 + q0;
    const float* xp = x + ((long)(b * 32 + i0) * 20) * 2;
    const float* w1p = w1 + lg * 8 * 128 + 64 * w + l15;   // col (4w+ct)*16+l15 via +16*ct

    // prefetch t=0
    float4 pdv0 = *(const float4*)dp,       pdv1 = *(const float4*)(dp + 4);
    float4 pbv0 = *(const float4*)bp,       pbv1 = *(const float4*)(bp + 4);
    float4 phv0 = *(const float4*)hp,       phv1 = *(const float4*)(hp + 4);
    float px0 = xp[0], px1 = xp[1];
    __syncthreads();
    const bool fast = (sFlag != 0);

    #pragma unroll 1
    for (int t = 0; t < 20; ++t) {
        // ===== phase A: wmat+normalize (regs), wN/xe stores; prefetch t+1 =====
        {
            float dvv[8], bvv[8], hvv[8];
            #pragma unroll
            for (int k = 0; k < 4; ++k) {
                dvv[k] = (&pdv0.x)[k]; dvv[4 + k] = (&pdv1.x)[k];
                bvv[k] = (&pbv0.x)[k]; bvv[4 + k] = (&pbv1.x)[k];
                hvv[k] = (&phv0.x)[k]; hvv[4 + k] = (&phv1.x)[k];
            }
            float xx0 = px0, xx1 = px1;
            if (t < 19) {
                pdv0 = *(const float4*)(dp + 32); pdv1 = *(const float4*)(dp + 36); dp += 32;
                if (!fast) {
                    pbv0 = *(const float4*)(bp + 32); pbv1 = *(const float4*)(bp + 36); bp += 32;
                    phv0 = *(const float4*)(hp + 32); phv1 = *(const float4*)(hp + 36); hp += 32;
                }
                px0 = xp[2]; px1 = xp[3]; xp += 2;
            }
            float wq[8];
            float inv;
            if (fast) {
                float s = 0.f;
                #pragma unroll
                for (int k = 0; k < 8; ++k) {
                    float v = dom0 - dvv[k];
                    wq[k] = v > 0.f ? v : 0.f;
                    s += wq[k];
                }
                s += __shfl_xor(s, 1); s += __shfl_xor(s, 2);
                inv = 1.0f / (s + 1e-8f);
            } else {
                float4 mj0 = *(const float4*)&sMaskT[t][q0];
                float4 mj1 = *(const float4*)&sMaskT[t][q0 + 4];
                float  mi  = sMaskT[t][i0];
                float s = 0.f;
                #pragma unroll
                for (int k = 0; k < 8; ++k) {
                    float bq = bvv[k], hq = hvv[k];
                    int ib = (int)floorf(bq * (1.0f / 30.0f)); ib = ib < 0 ? 0 : (ib > 11 ? 11 : ib);
                    int ih = (int)floorf(hq * (1.0f / 30.0f)); ih = ih < 0 ? 0 : (ih > 11 ? 11 : ih);
                    float v = sDom[ib * 12 + ih] - dvv[k];
                    v = v > 0.f ? v : 0.f;
                    float m = (k < 4) ? (&mj0.x)[k] : (&mj1.x)[k - 4];
                    wq[k] = v * m;
                    s += wq[k];
                }
                s += __shfl_xor(s, 1); s += __shfl_xor(s, 2);
                inv = mi / (mi * s + 1e-8f);
            }
            bf16x8 wn8;
            #pragma unroll
            for (int k = 0; k < 8; ++k) wn8[k] = (__bf16)(wq[k] * inv);
            *(bf16x8*)&sWN[i0][q0] = wn8;
            bf16x4 xv;
            #pragma unroll
            for (int k = 0; k < 4; ++k)
                xv[k] = (__bf16)(xx0 * ewa[k] + xx1 * ewb[k] + ebb[k]);
            *(bf16x4*)&sAin[i0][e0] = xv;
        }
        __syncthreads();                                   // s1

        // ===== phase B: gates (4 col-tiles/wave) + lane-local cell + online z1 + w1 stream =====
        {
            bf16x8 bxh[2][2];
            #pragma unroll
            for (int nt = 0; nt < 2; ++nt)
                #pragma unroll
                for (int kt = 0; kt < 2; ++kt)
                    bxh[nt][kt] = *(const bf16x8*)&sAin[nt * 16 + l15][kt * 32 + lg * 8];
            if (t >= 1) {     // z1 += h_{t-1} @ w1[(t-1)*32:]
                bf16x8 az[2];
                #pragma unroll
                for (int mt = 0; mt < 2; ++mt)
                    az[mt] = *(const bf16x8*)&sAin[mt * 16 + l15][16 + lg * 8];
                #pragma unroll
                for (int mt = 0; mt < 2; ++mt)
                    #pragma unroll
                    for (int ct = 0; ct < 4; ++ct)
                        accZ[mt][ct] = MFMA(az[mt], Bw1cur[ct], accZ[mt][ct]);
            }
            #pragma unroll
            for (int mtl = 0; mtl < 4; ++mtl)
                #pragma unroll
                for (int nt = 0; nt < 2; ++nt) {
                    f32x4 cc = {0.f, 0.f, 0.f, 0.f};
                    cc = MFMA(Ag[mtl][0], bxh[nt][0], cc);
                    cc = MFMA(Ag[mtl][1], bxh[nt][1], cc);
                    // lane holds i,f,g,o (q=0..3) for n=nt*16+l15, h=4*(4w+mtl)... /4 = (4w+mtl)*4+lg
                    float cn = sigf(cc[1]) * cst[mtl][nt] + sigf(cc[0]) * tanhf_(cc[2]);
                    cst[mtl][nt] = cn;
                    sHl[nt * 16 + l15][4 * (4 * w + mtl) + lg] = (__bf16)(sigf(cc[3]) * tanhf_(cn));
                }
            #pragma unroll
            for (int ct = 0; ct < 4; ++ct)     // stream w1 rows t*32.. (used t+1 / tail)
                #pragma unroll
                for (int j = 0; j < 8; ++j)
                    Bw1cur[ct][j] = (__bf16)w1p[j * 128 + ct * 16];
            w1p += 4096;
        }
        __syncthreads();                                   // s2

        // ===== phase C: ha col-half cw, BOTH row halves -> sPA[:,cw], sHaT rows cw (full) =====
        #pragma unroll
        for (int mtw = 0; mtw < 2; ++mtw) {
            bf16x8 a = *(const bf16x8*)&sHl[mtw * 16 + l15][lg * 8];
            f32x4 cc = {0.f, 0.f, 0.f, 0.f};
            cc = MFMA(a, Be2a, cc);
            bf16x4 tv;
            #pragma unroll
            for (int q = 0; q < 4; ++q) {
                float v = cc[q] + bEw;
                tv[q] = (__bf16)v;
                sPA[mtw * 16 + 4 * lg + q][cw] = (__bf16)v;
            }
            *(bf16x4*)&sHaT[cw][mtw * 16 + 4 * lg] = tv;
        }
        // NO barrier: D reads sHaT rows cw (cols 0..31) — fully written by THIS wave above.

        // ===== phase D: att col-half cw, both row halves =====
        {
            bf16x8 bT = *(const bf16x8*)&sHaT[w * 16 + l15][lg * 8];
            #pragma unroll
            for (int mtw = 0; mtw < 2; ++mtw) {
                bf16x8 aW = *(const bf16x8*)&sWN[mtw * 16 + l15][lg * 8];
                f32x4 cc = {0.f, 0.f, 0.f, 0.f};
                cc = MFMA(aW, bT, cc);
                #pragma unroll
                for (int q = 0; q < 4; ++q)
                    sPA[mtw * 16 + 4 * lg + q][32 + cw] = (__bf16)cc[q];
            }
        }
        __syncthreads();                                   // s4 (cross-wave: sPA col halves)

        // ===== phase E: emb col-half cw, both row halves =====
        #pragma unroll
        for (int mtw = 0; mtw < 2; ++mtw) {
            bf16x8 a0 = *(const bf16x8*)&sPA[mtw * 16 + l15][lg * 8];
            bf16x8 a1 = *(const bf16x8*)&sPA[mtw * 16 + l15][32 + lg * 8];
            f32x4 cc = {0.f, 0.f, 0.f, 0.f};
            cc = MFMA(a0, Bsp[0], cc);
            cc = MFMA(a1, Bsp[1], cc);
            #pragma unroll
            for (int q = 0; q < 4; ++q)
                sEmb[mtw * 16 + 4 * lg + q][cw] = (__bf16)tanhf_(cc[q] + bSw);
        }
        __syncthreads();                                   // s5 (cross-wave: sEmb col halves)

        // ===== phase F: h_new col-half cw, both row halves -> sAin cols 16-47 =====
        #pragma unroll
        for (int mtw = 0; mtw < 2; ++mtw) {
            bf16x8 ae = *(const bf16x8*)&sEmb[mtw * 16 + l15][lg * 8];
            f32x4 cf = {0.f, 0.f, 0.f, 0.f};
            cf = MFMA(ae, Ba2e, cf);
            #pragma unroll
            for (int q = 0; q < 4; ++q)
                sAin[mtw * 16 + 4 * lg + q][16 + cw] = (__bf16)(cf[q] + bAw);
        }
        // no barrier: next-iteration s1 orders F -> B(t+1); A(t+1) writes disjoint LDS
    }

    // ================= tail =================
    __syncthreads();
    // final z1 accumulate (h_19 with w1 rows 608-639)
    {
        bf16x8 az[2];
        #pragma unroll
        for (int mt = 0; mt < 2; ++mt)
            az[mt] = *(const bf16x8*)&sAin[mt * 16 + l15][16 + lg * 8];
        #pragma unroll
        for (int mt = 0; mt < 2; ++mt)
            #pragma unroll
            for (int ct = 0; ct < 4; ++ct)
                accZ[mt][ct] = MFMA(az[mt], Bw1cur[ct], accZ[mt][ct]);
    }
    // z1 = leaky(accZ + b1)
    #pragma unroll
    for (int mt = 0; mt < 2; ++mt)
        #pragma unroll
        for (int ct = 0; ct < 4; ++ct) {
            int c = (4 * w + ct) * 16 + l15;
            float bias = b1[c];
            #pragma unroll
            for (int q = 0; q < 4; ++q) {
                float v = accZ[mt][ct][q] + bias;
                v = v > 0.f ? v : 0.2f * v;
                z1bf[mt * 16 + 4 * lg + q][c] = (__bf16)v;
            }
        }
    __syncthreads();

    // z2 = leaky(z1 @ w2 + b2), K=128; wave owns 4 col-tiles
    {
        f32x4 c2[2][4] = {};
        #pragma unroll
        for (int kt = 0; kt < 4; ++kt) {
            bf16x8 a[2];
            #pragma unroll
            for (int mt = 0; mt < 2; ++mt)
                a[mt] = *(const bf16x8*)&z1bf[mt * 16 + l15][kt * 32 + lg * 8];
            #pragma unroll
            for (int ct = 0; ct < 4; ++ct) {
                bf16x8 bw2;
                int c = (4 * w + ct) * 16 + l15;
                #pragma unroll
                for (int j = 0; j < 8; ++j)
                    bw2[j] = (__bf16)w2[(kt * 32 + lg * 8 + j) * 128 + c];
                #pragma unroll
                for (int mt = 0; mt < 2; ++mt)
                    c2[mt][ct] = MFMA(a[mt], bw2, c2[mt][ct]);
            }
        }
        #pragma unroll
        for (int mt = 0; mt < 2; ++mt)
            #pragma unroll
            for (int ct = 0; ct < 4; ++ct) {
                int c = (4 * w + ct) * 16 + l15;
                float bias = b2[c];
                #pragma unroll
                for (int q = 0; q < 4; ++q) {
                    float v = c2[mt][ct][q] + bias;
                    v = v > 0.f ? v : 0.2f * v;
                    z2bf[mt * 16 + 4 * lg + q][c] = (__bf16)v;
                }
            }
    }
    __syncthreads();

    // z3 = sigmoid(z2 @ w3 + b3): 4 lanes per row, 32 cols each
    {
        int n = tid >> 2, kg = tid & 3;
        float s = 0.f;
        #pragma unroll
        for (int p = 0; p < 4; ++p) {
            bf16x8 v = *(const bf16x8*)&z2bf[n][kg * 32 + p * 8];
            #pragma unroll
            for (int j = 0; j < 8; ++j)
                s += (float)v[j] * w3[kg * 32 + p * 8 + j];
        }
        s += __shfl_xor(s, 1); s += __shfl_xor(s, 2);
        if (kg == 0) out[b * 32 + n] = sigf(s + b3[0]);
    }
}

extern "C" void kernel_launch(void* const* d_in, const int* in_sizes, int n_in,
                              void* d_out, int out_size, void* d_ws, size_t ws_size,
                              hipStream_t stream) {
    (void)in_sizes; (void)n_in; (void)d_ws; (void)ws_size; (void)out_size;
    const float* x     = (const float*)d_in[0];
    const float* dmat  = (const float*)d_in[1];
    const float* bmat  = (const float*)d_in[2];
    const float* hmat  = (const float*)d_in[3];
    const float* mask  = (const float*)d_in[4];
    const float* emb_w = (const float*)d_in[5];
    const float* emb_b = (const float*)d_in[6];
    const float* w_ih  = (const float*)d_in[7];
    const float* w_hh  = (const float*)d_in[8];
    const float* b_ih  = (const float*)d_in[9];
    const float* b_hh  = (const float*)d_in[10];
    const float* e2a_w = (const float*)d_in[11];
    const float* e2a_b = (const float*)d_in[12];
    const float* dom   = (const float*)d_in[13];
    const float* sp_w  = (const float*)d_in[14];
    const float* sp_b  = (const float*)d_in[15];
    const float* a2e_w = (const float*)d_in[16];
    const float* a2e_b = (const float*)d_in[17];
    const float* w1    = (const float*)d_in[18];
    const float* b1    = (const float*)d_in[19];
    const float* w2    = (const float*)d_in[20];
    const float* b2    = (const float*)d_in[21];
    const float* w3    = (const float*)d_in[22];
    const float* b3    = (const float*)d_in[23];
    float* out = (float*)d_out;

    traj_disc_kernel<<<dim3(TD_B), dim3(128), 0, stream>>>(
        x, dmat, bmat, hmat, mask, emb_w, emb_b, w_ih, w_hh, b_ih, b_hh,
        e2a_w, e2a_b, dom, sp_w, sp_b, a2e_w, a2e_b,
        w1, b1, w2, b2, w3, b3, out);
}

// Round 14
// 69.834 us; speedup vs baseline: 1.5320x; 1.5320x over previous
//
#include <hip/hip_runtime.h>
#include <hip/hip_bf16.h>

#define TD_B 512

typedef __bf16 bf16x8 __attribute__((ext_vector_type(8)));
typedef __bf16 bf16x4 __attribute__((ext_vector_type(4)));
typedef float  f32x4  __attribute__((ext_vector_type(4)));

#define MFMA(a, b, c) __builtin_amdgcn_mfma_f32_16x16x32_bf16((a), (b), (c), 0, 0, 0)

__device__ __forceinline__ float sigf(float x)  { return 1.0f / (1.0f + __expf(-x)); }
__device__ __forceinline__ float tanhf_(float x){ return 2.0f / (1.0f + __expf(-2.0f * x)) - 1.0f; }

// LDS-only barrier: orders ds_write->ds_read across waves WITHOUT draining
// outstanding global loads (vmcnt), so register prefetches stay in flight
// across barriers. __syncthreads would emit s_waitcnt vmcnt(0) lgkmcnt(0).
__device__ __forceinline__ void sync_lds() {
    __builtin_amdgcn_sched_barrier(0);
    asm volatile("s_waitcnt lgkmcnt(0)" ::: "memory");
    __builtin_amdgcn_s_barrier();
    __builtin_amdgcn_sched_barrier(0);
}

extern "C" __global__ void __launch_bounds__(256, 2)
traj_disc_kernel(const float* __restrict__ x, const float* __restrict__ dmat,
                 const float* __restrict__ bmat, const float* __restrict__ hmat,
                 const float* __restrict__ mask,
                 const float* __restrict__ emb_w, const float* __restrict__ emb_b,
                 const float* __restrict__ w_ih, const float* __restrict__ w_hh,
                 const float* __restrict__ b_ih, const float* __restrict__ b_hh,
                 const float* __restrict__ e2a_w, const float* __restrict__ e2a_b,
                 const float* __restrict__ dom,
                 const float* __restrict__ sp_w, const float* __restrict__ sp_b,
                 const float* __restrict__ a2e_w, const float* __restrict__ a2e_b,
                 const float* __restrict__ w1, const float* __restrict__ b1,
                 const float* __restrict__ w2, const float* __restrict__ b2,
                 const float* __restrict__ w3, const float* __restrict__ b3,
                 float* __restrict__ out)
{
    const int b    = blockIdx.x;
    const int tid  = threadIdx.x;
    const int lane = tid & 63;
    const int w    = tid >> 6;       // wave 0..3
    const int l15  = lane & 15;
    const int lg   = lane >> 4;      // 0..3

    __shared__ __bf16 sAin[32][72];   // 0-15 xe | 16-47 h | 48 ones | 49-63 zero
    __shared__ __bf16 sHl [32][40];
    __shared__ __bf16 sWN [32][40];
    __shared__ __bf16 sHaT[32][40];
    __shared__ __bf16 sEmb[32][40];
    __shared__ __bf16 sPA [32][72];   // 0-31 ha | 32-63 att
    __shared__ float  sMaskT[20][36];
    __shared__ float  sDom[144];
    __shared__ __bf16 z1bf[32][136];
    __shared__ __bf16 z2bf[32][136];
    __shared__ int    sFlag;

    // ---- staging ----
    if (tid == 0) sFlag = 1;
    for (int idx = tid; idx < 32 * 72; idx += 256)
        (&sAin[0][0])[idx] = (idx % 72 == 48) ? (__bf16)1.0f : (__bf16)0.0f;
    for (int idx = tid; idx < 640; idx += 256) {
        int tt = idx >> 5, n = idx & 31;
        sMaskT[tt][n] = mask[(b * 32 + n) * 20 + tt];
    }
    if (tid < 144) sDom[tid] = dom[tid];
    __syncthreads();
    // uniformity check (deterministic, input-dependent): dom all-equal AND mask all-ones
    {
        const float d0 = sDom[0];
        bool ok = true;
        for (int i = tid; i < 144; i += 256) ok &= (sDom[i] == d0);
        for (int i = tid; i < 640; i += 256) ok &= ((&sMaskT[0][0])[(i >> 5) * 36 + (i & 31)] == 1.0f);
        if (!ok) sFlag = 0;
    }

    // phase-A per-thread constants
    const int i0 = tid >> 3, p0 = tid & 7;
    const float dom0 = dom[0];
    const float ewa0 = emb_w[2 * p0],      ewa1 = emb_w[2 * p0 + 1];
    const float ewb0 = emb_w[16 + 2 * p0], ewb1 = emb_w[16 + 2 * p0 + 1];
    const float eb0  = emb_b[2 * p0],      eb1  = emb_b[2 * p0 + 1];

    // ---- transposed-gates A-fragments (gate-interleaved cols c=4h+g) ----
    bf16x8 Ag[2][2];
    #pragma unroll
    for (int mtl = 0; mtl < 2; ++mtl) {
        int c  = (2 * w + mtl) * 16 + l15;
        int cg = (c & 3) * 32 + (c >> 2);
        #pragma unroll
        for (int kt = 0; kt < 2; ++kt)
            #pragma unroll
            for (int j = 0; j < 8; ++j) {
                int k = kt * 32 + lg * 8 + j;
                float v;
                if (k < 16)       v = w_ih[k * 128 + cg];
                else if (k < 48)  v = w_hh[(k - 16) * 128 + cg];
                else if (k == 48) v = b_ih[cg] + b_hh[cg];
                else              v = 0.0f;
                Ag[mtl][kt][j] = (__bf16)v;
            }
    }
    // wave roles for C/D/E/F: row-half mtw, col-half ntw
    const int mtw = w >> 1, ntw = w & 1;
    const int cw  = ntw * 16 + l15;
    bf16x8 Be2a, Ba2e, Bsp[2];
    #pragma unroll
    for (int j = 0; j < 8; ++j) {
        Be2a[j] = (__bf16)e2a_w[(lg * 8 + j) * 32 + cw];
        Ba2e[j] = (__bf16)a2e_w[(lg * 8 + j) * 32 + cw];
    }
    #pragma unroll
    for (int kt = 0; kt < 2; ++kt)
        #pragma unroll
        for (int j = 0; j < 8; ++j)
            Bsp[kt][j] = (__bf16)sp_w[(kt * 32 + lg * 8 + j) * 32 + cw];
    const float bEw = e2a_b[cw], bSw = sp_b[cw], bAw = a2e_b[cw];

    float cst[2][2] = {{0.f, 0.f}, {0.f, 0.f}};  // cell state [mtl][nt], lane-local
    f32x4 accZ[2][2] = {};                       // online z1 [mt][ntp]
    bf16x8 Bw1cur[2];

    // incremental pointers (t-stride: dmat/bmat/hmat = 32 floats; x = 2; w1 = 4096)
    const float* dp = dmat + ((long)(b * 32 + i0) * 20) * 32 + 4 * p0;
    const float* bp = bmat + ((long)(b * 32 + i0) * 20) * 32 + 4 * p0;
    const float* hp = hmat + ((long)(b * 32 + i0) * 20) * 32 + 4 * p0;
    const float* xp = x + ((long)(b * 32 + i0) * 20) * 2;
    const float* w1p = w1 + lg * 8 * 128 + 32 * w + l15;   // rows lg*8.., col c(ntp=0); +16 for ntp=1

    // prefetch t=0 inputs
    float4 pdv = *(const float4*)dp;
    float4 pbv = *(const float4*)bp;
    float4 phv = *(const float4*)hp;
    float px0 = xp[0], px1 = xp[1];
    __syncthreads();
    const bool fast = (sFlag != 0);   // block-uniform

    #pragma unroll 1
    for (int t = 0; t < 20; ++t) {
        // ===== phase A: wmat+normalize (regs), wN/xe stores; prefetch t+1 =====
        {
            float4 dv = pdv, bv = pbv, hv = phv;
            float xx0 = px0, xx1 = px1;
            if (t < 19) {
                pdv = *(const float4*)(dp + 32); dp += 32;
                if (!fast) {
                    pbv = *(const float4*)(bp + 32); bp += 32;
                    phv = *(const float4*)(hp + 32); hp += 32;
                }
                px0 = xp[2]; px1 = xp[3]; xp += 2;
            }
            float wq[4];
            float inv;
            if (fast) {
                #pragma unroll
                for (int q = 0; q < 4; ++q) {
                    float v = dom0 - (&dv.x)[q];
                    wq[q] = v > 0.f ? v : 0.f;
                }
                float s = wq[0] + wq[1] + wq[2] + wq[3];
                s += __shfl_xor(s, 1); s += __shfl_xor(s, 2); s += __shfl_xor(s, 4);
                inv = 1.0f / (s + 1e-8f);
            } else {
                float4 mj = *(const float4*)&sMaskT[t][4 * p0];
                float  mi = sMaskT[t][i0];
                #pragma unroll
                for (int q = 0; q < 4; ++q) {
                    float bq = (&bv.x)[q], hq = (&hv.x)[q];
                    int ib = (int)floorf(bq * (1.0f / 30.0f)); ib = ib < 0 ? 0 : (ib > 11 ? 11 : ib);
                    int ih = (int)floorf(hq * (1.0f / 30.0f)); ih = ih < 0 ? 0 : (ih > 11 ? 11 : ih);
                    float v = sDom[ib * 12 + ih] - (&dv.x)[q];
                    v = v > 0.f ? v : 0.f;
                    wq[q] = v * (&mj.x)[q];
                }
                float s = wq[0] + wq[1] + wq[2] + wq[3];
                s += __shfl_xor(s, 1); s += __shfl_xor(s, 2); s += __shfl_xor(s, 4);
                inv = mi / (mi * s + 1e-8f);
            }
            bf16x4 wn4;
            #pragma unroll
            for (int q = 0; q < 4; ++q) wn4[q] = (__bf16)(wq[q] * inv);
            *(bf16x4*)&sWN[i0][4 * p0] = wn4;
            sAin[i0][2 * p0]     = (__bf16)(xx0 * ewa0 + xx1 * ewb0 + eb0);
            sAin[i0][2 * p0 + 1] = (__bf16)(xx0 * ewa1 + xx1 * ewb1 + eb1);
        }
        sync_lds();                                        // s1 (LDS-only)

        // ===== phase B: transposed gates + lane-local cell + online z1 + w1 stream =====
        {
            bf16x8 bxh[2][2];
            #pragma unroll
            for (int nt = 0; nt < 2; ++nt)
                #pragma unroll
                for (int kt = 0; kt < 2; ++kt)
                    bxh[nt][kt] = *(const bf16x8*)&sAin[nt * 16 + l15][kt * 32 + lg * 8];
            if (t >= 1) {     // z1 += h_{t-1} @ w1[(t-1)*32:]
                bf16x8 az[2];
                #pragma unroll
                for (int mt = 0; mt < 2; ++mt)
                    az[mt] = *(const bf16x8*)&sAin[mt * 16 + l15][16 + lg * 8];
                #pragma unroll
                for (int mt = 0; mt < 2; ++mt)
                    #pragma unroll
                    for (int ntp = 0; ntp < 2; ++ntp)
                        accZ[mt][ntp] = MFMA(az[mt], Bw1cur[ntp], accZ[mt][ntp]);
            }
            #pragma unroll
            for (int mtl = 0; mtl < 2; ++mtl)
                #pragma unroll
                for (int nt = 0; nt < 2; ++nt) {
                    f32x4 cc = {0.f, 0.f, 0.f, 0.f};
                    cc = MFMA(Ag[mtl][0], bxh[nt][0], cc);
                    cc = MFMA(Ag[mtl][1], bxh[nt][1], cc);
                    float cn = sigf(cc[1]) * cst[mtl][nt] + sigf(cc[0]) * tanhf_(cc[2]);
                    cst[mtl][nt] = cn;
                    sHl[nt * 16 + l15][4 * (2 * w + mtl) + lg] = (__bf16)(sigf(cc[3]) * tanhf_(cn));
                }
            #pragma unroll
            for (int ntp = 0; ntp < 2; ++ntp)     // stream w1 rows t*32.. (used t+1 / tail)
                #pragma unroll
                for (int j = 0; j < 8; ++j)
                    Bw1cur[ntp][j] = (__bf16)w1p[j * 128 + ntp * 16];
            w1p += 4096;
        }
        sync_lds();                                        // s2 (LDS-only)

        // ===== phase C: ha tile -> sPA[:,0:32], sHaT =====
        {
            bf16x8 a = *(const bf16x8*)&sHl[mtw * 16 + l15][lg * 8];
            f32x4 cc = {0.f, 0.f, 0.f, 0.f};
            cc = MFMA(a, Be2a, cc);
            bf16x4 tv;
            #pragma unroll
            for (int q = 0; q < 4; ++q) {
                float v = cc[q] + bEw;
                tv[q] = (__bf16)v;
                sPA[mtw * 16 + 4 * lg + q][cw] = (__bf16)v;
            }
            *(bf16x4*)&sHaT[cw][mtw * 16 + 4 * lg] = tv;
        }
        sync_lds();                                        // s3 (LDS-only)

        // ===== phase D: att = wN @ ha -> sPA[:,32:64] =====
        {
            bf16x8 aW = *(const bf16x8*)&sWN [mtw * 16 + l15][lg * 8];
            bf16x8 bT = *(const bf16x8*)&sHaT[cw][lg * 8];
            f32x4 cc = {0.f, 0.f, 0.f, 0.f};
            cc = MFMA(aW, bT, cc);
            #pragma unroll
            for (int q = 0; q < 4; ++q)
                sPA[mtw * 16 + 4 * lg + q][32 + cw] = (__bf16)cc[q];
        }
        sync_lds();                                        // s4 (LDS-only)

        // ===== phase E: emb = tanh([ha|att] @ sp + b) =====
        {
            bf16x8 a0 = *(const bf16x8*)&sPA[mtw * 16 + l15][lg * 8];
            bf16x8 a1 = *(const bf16x8*)&sPA[mtw * 16 + l15][32 + lg * 8];
            f32x4 cc = {0.f, 0.f, 0.f, 0.f};
            cc = MFMA(a0, Bsp[0], cc);
            cc = MFMA(a1, Bsp[1], cc);
            #pragma unroll
            for (int q = 0; q < 4; ++q)
                sEmb[mtw * 16 + 4 * lg + q][cw] = (__bf16)tanhf_(cc[q] + bSw);
        }
        sync_lds();                                        // s5 (LDS-only)

        // ===== phase F: h_new = emb @ a2e + b -> sAin cols 16-47 =====
        {
            bf16x8 a = *(const bf16x8*)&sEmb[mtw * 16 + l15][lg * 8];
            f32x4 cc = {0.f, 0.f, 0.f, 0.f};
            cc = MFMA(a, Ba2e, cc);
            #pragma unroll
            for (int q = 0; q < 4; ++q)
                sAin[mtw * 16 + 4 * lg + q][16 + cw] = (__bf16)(cc[q] + bAw);
        }
        // no barrier here: next-iteration s1 orders F/A -> B(t+1); A(t+1) writes disjoint LDS
    }

    // ================= tail =================
    __syncthreads();
    // final z1 accumulate (h_19 with w1 rows 608-639)
    {
        bf16x8 az[2];
        #pragma unroll
        for (int mt = 0; mt < 2; ++mt)
            az[mt] = *(const bf16x8*)&sAin[mt * 16 + l15][16 + lg * 8];
        #pragma unroll
        for (int mt = 0; mt < 2; ++mt)
            #pragma unroll
            for (int ntp = 0; ntp < 2; ++ntp)
                accZ[mt][ntp] = MFMA(az[mt], Bw1cur[ntp], accZ[mt][ntp]);
    }
    // z1 = leaky(accZ + b1)
    #pragma unroll
    for (int mt = 0; mt < 2; ++mt)
        #pragma unroll
        for (int ntp = 0; ntp < 2; ++ntp) {
            int c = (2 * w + ntp) * 16 + l15;
            float bias = b1[c];
            #pragma unroll
            for (int q = 0; q < 4; ++q) {
                float v = accZ[mt][ntp][q] + bias;
                v = v > 0.f ? v : 0.2f * v;
                z1bf[mt * 16 + 4 * lg + q][c] = (__bf16)v;
            }
        }
    __syncthreads();

    // z2 = leaky(z1 @ w2 + b2), K=128
    {
        f32x4 c2[2][2] = {};
        #pragma unroll
        for (int kt = 0; kt < 4; ++kt) {
            bf16x8 a[2];
            #pragma unroll
            for (int mt = 0; mt < 2; ++mt)
                a[mt] = *(const bf16x8*)&z1bf[mt * 16 + l15][kt * 32 + lg * 8];
            bf16x8 bb[2];
            #pragma unroll
            for (int ntp = 0; ntp < 2; ++ntp) {
                int c = (2 * w + ntp) * 16 + l15;
                #pragma unroll
                for (int j = 0; j < 8; ++j)
                    bb[ntp][j] = (__bf16)w2[(kt * 32 + lg * 8 + j) * 128 + c];
            }
            #pragma unroll
            for (int mt = 0; mt < 2; ++mt)
                #pragma unroll
                for (int ntp = 0; ntp < 2; ++ntp)
                    c2[mt][ntp] = MFMA(a[mt], bb[ntp], c2[mt][ntp]);
        }
        #pragma unroll
        for (int mt = 0; mt < 2; ++mt)
            #pragma unroll
            for (int ntp = 0; ntp < 2; ++ntp) {
                int c = (2 * w + ntp) * 16 + l15;
                float bias = b2[c];
                #pragma unroll
                for (int q = 0; q < 4; ++q) {
                    float v = c2[mt][ntp][q] + bias;
                    v = v > 0.f ? v : 0.2f * v;
                    z2bf[mt * 16 + 4 * lg + q][c] = (__bf16)v;
                }
            }
    }
    __syncthreads();

    // z3 = sigmoid(z2 @ w3 + b3)
    {
        int n = tid >> 3, kg = tid & 7;
        bf16x8 v0 = *(const bf16x8*)&z2bf[n][kg * 16];
        bf16x8 v1 = *(const bf16x8*)&z2bf[n][kg * 16 + 8];
        float s = 0.f;
        #pragma unroll
        for (int j = 0; j < 8; ++j)
            s += (float)v0[j] * w3[kg * 16 + j] + (float)v1[j] * w3[kg * 16 + 8 + j];
        s += __shfl_xor(s, 1); s += __shfl_xor(s, 2); s += __shfl_xor(s, 4);
        if (kg == 0) out[b * 32 + n] = sigf(s + b3[0]);
    }
}

extern "C" void kernel_launch(void* const* d_in, const int* in_sizes, int n_in,
                              void* d_out, int out_size, void* d_ws, size_t ws_size,
                              hipStream_t stream) {
    (void)in_sizes; (void)n_in; (void)d_ws; (void)ws_size; (void)out_size;
    const float* x     = (const float*)d_in[0];
    const float* dmat  = (const float*)d_in[1];
    const float* bmat  = (const float*)d_in[2];
    const float* hmat  = (const float*)d_in[3];
    const float* mask  = (const float*)d_in[4];
    const float* emb_w = (const float*)d_in[5];
    const float* emb_b = (const float*)d_in[6];
    const float* w_ih  = (const float*)d_in[7];
    const float* w_hh  = (const float*)d_in[8];
    const float* b_ih  = (const float*)d_in[9];
    const float* b_hh  = (const float*)d_in[10];
    const float* e2a_w = (const float*)d_in[11];
    const float* e2a_b = (const float*)d_in[12];
    const float* dom   = (const float*)d_in[13];
    const float* sp_w  = (const float*)d_in[14];
    const float* sp_b  = (const float*)d_in[15];
    const float* a2e_w = (const float*)d_in[16];
    const float* a2e_b = (const float*)d_in[17];
    const float* w1    = (const float*)d_in[18];
    const float* b1    = (const float*)d_in[19];
    const float* w2    = (const float*)d_in[20];
    const float* b2    = (const float*)d_in[21];
    const float* w3    = (const float*)d_in[22];
    const float* b3    = (const float*)d_in[23];
    float* out = (float*)d_out;

    traj_disc_kernel<<<dim3(TD_B), dim3(256), 0, stream>>>(
        x, dmat, bmat, hmat, mask, emb_w, emb_b, w_ih, w_hh, b_ih, b_hh,
        e2a_w, e2a_b, dom, sp_w, sp_b, a2e_w, a2e_b,
        w1, b1, w2, b2, w3, b3, out);
}